// Round 22
// baseline (119.347 us; speedup 1.0000x reference)
//
#include <hip/hip_runtime.h>
#include <cstdint>
#include <cstddef>

typedef __attribute__((ext_vector_type(8))) short bf8_t;    // 8 x bf16 bits
typedef __attribute__((ext_vector_type(4))) float f4_t;
typedef __attribute__((ext_vector_type(16))) float f16v_t;
typedef __attribute__((ext_vector_type(2))) unsigned u2_t;
typedef __attribute__((ext_vector_type(4))) unsigned u4_t;

#define DEVFN static __device__ __forceinline__
#define MFMA16(a, b, c) __builtin_amdgcn_mfma_f32_16x16x32_bf16(a, b, c, 0, 0, 0)
#define MFMA32(a, b, c) __builtin_amdgcn_mfma_f32_32x32x16_bf16(a, b, c, 0, 0, 0)

// 768^-0.5 * log2(e): folded into Q at GEMM1 epilogue; attn uses exp2 directly.
constexpr float kQscale = 0.05205877317700523f;

DEVFN short f2bs(float f) {  // f32 -> bf16 bits, RNE
  uint32_t u = __builtin_bit_cast(uint32_t, f);
  u = (u + 0x7FFFu + ((u >> 16) & 1u)) >> 16;
  return (short)(uint16_t)u;
}

DEVFN unsigned cvtpk(float lo, float hi) {  // packed bf16(lo) | bf16(hi)<<16
  unsigned r;
  asm("v_cvt_pk_bf16_f32 %0, %1, %2" : "=v"(r) : "v"(lo), "v"(hi));
  return r;
}

DEVFN float red2_sum(float v) { return v + __shfl_xor(v, 32, 64); }

// async global->LDS, 16B/lane; dest = lds_ptr + lane*16 (wave-uniform base)
DEVFN void gload16(const void* g, void* l) {
  __builtin_amdgcn_global_load_lds(
      (const __attribute__((address_space(1))) void*)g,
      (__attribute__((address_space(3))) void*)l, 16, 0, 0);
}

// -------------------------------------------- fused pre-pass (1 launch, was 3)
// blocks [0,3072): x f32 -> bf16;  [3072,4800): w_attn^T;  [4800,5376): w_proj^T
__global__ __launch_bounds__(256) void prep(const float* __restrict__ x,
                                            short* __restrict__ xb,
                                            const float* __restrict__ w_attn,
                                            short* __restrict__ wat,
                                            const float* __restrict__ w_proj,
                                            short* __restrict__ wpt) {
  __shared__ float tile[32][33];
  const int blk = blockIdx.x, tid = threadIdx.x;
  if (blk < 3072) {                                // cvt: one bf8 chunk/thread
    const int i = blk * 256 + tid;
    const f4_t* p = (const f4_t*)x + (size_t)i * 2;
    f4_t a = p[0], b = p[1];
    bf8_t h;
    h[0] = f2bs(a[0]); h[1] = f2bs(a[1]); h[2] = f2bs(a[2]); h[3] = f2bs(a[3]);
    h[4] = f2bs(b[0]); h[5] = f2bs(b[1]); h[6] = f2bs(b[2]); h[7] = f2bs(b[3]);
    *((bf8_t*)xb + i) = h;
    return;
  }
  const float* w;
  short* wT;
  int N, n0, k0;
  if (blk < 4800) {                                // w_attn [768][2304] -> ^T
    const int bb = blk - 3072;
    w = w_attn; wT = wat; N = 2304;
    n0 = (bb % 72) << 5; k0 = (bb / 72) << 5;
  } else {                                         // w_proj [768][768] -> ^T
    const int bb = blk - 4800;
    w = w_proj; wT = wpt; N = 768;
    n0 = (bb % 24) << 5; k0 = (bb / 24) << 5;
  }
  const int tx = tid & 31, ty = tid >> 5;          // (32, 8)
#pragma unroll
  for (int i = 0; i < 4; ++i)
    tile[ty * 4 + i][tx] = w[(size_t)(k0 + ty * 4 + i) * N + n0 + tx];
  __syncthreads();
#pragma unroll
  for (int i = 0; i < 4; ++i)
    wT[(size_t)(n0 + ty * 4 + i) * 768 + k0 + tx] = f2bs(tile[tx][ty * 4 + i]);
}

// ------------------------------------------------------------------ bf16 GEMM
// C[M][N] = A[M][K] @ Bt[N][K]^T + bias.  BMxBN tile, BK=64, NW waves
// (wave grid BM/64 x NW/(BM/64)). K-loop = R19/R21 proven schedule: A dbuf +
// B single-buffered via reg-hoist (B-frags+A-kk0 to regs -> barrier1 ->
// stage A(t+1)^buf + B(t+1) same buffer -> MFMA kk0 -> A-kk1 frags -> MFMA
// kk1 -> barrier2). R22: BM=256 for QKV GEMM -> grid 576 = 1.125 resident
// rounds (was 1152 @ 3/CU = 1.5 rounds, ~15% tail) and 2x FLOP per barrier
// pair. Epilogue handles BM/128 row-halves through the same swizzled
// T[128][132] path. + XCD-grouped swizzle, gload_lds(16B) pre-swizzled src.
template <int EPI, int BM, int BN, int NW>
__global__ __launch_bounds__(NW * 64) void gemm_bf16(
    const short* __restrict__ A, const short* __restrict__ Bt,
    const float* __restrict__ bias, float* __restrict__ outF,
    short* __restrict__ qb, short* __restrict__ kb, short* __restrict__ vtb,
    int Mdim, int Ndim, int Kdim) {
  constexpr int NT = NW * 64;                      // threads
  constexpr int WCM = BM / 64;                     // waves in m-dir
  constexpr int WCN = NW / WCM;                    // waves in n-dir
  constexpr int WNW = BN / WCN;                    // wave n-width
  constexpr int NI = WNW / 16;                     // n-frags per wave
  constexpr int ACH = (BM >> 3) / NW;              // A 1KB chunks per wave
  constexpr int BCH = (BN >> 3) / NW;              // B 1KB chunks per wave
  constexpr int ABYTES = BM << 7;                  // A tile bytes
  __shared__ char smem[2 * ABYTES + (BN << 7)];    // A dbuf | B single
  const int nbx = gridDim.x;
  const int bid = blockIdx.x + nbx * blockIdx.y;
  const int xcd = bid & 7, slot = bid >> 3;        // dispatch round-robins XCDs
  const int mp = xcd + ((slot / nbx) << 3);        // bijective remap
  const int np = slot % nbx;
  const int m0 = mp * BM, n0 = np * BN;
  const int tid = threadIdx.x;
  const int lane = tid & 63, wid = tid >> 6;
  const int wr = wid / WCN, wc = wid % WCN;
  const int g = lane >> 4, cl = lane & 15;
  const int ldb = Kdim << 1;                       // global row stride, bytes

  f4_t acc[4][NI];
#pragma unroll
  for (int mi = 0; mi < 4; ++mi)
#pragma unroll
    for (int ni = 0; ni < NI; ++ni) acc[mi][ni] = (f4_t){0.f, 0.f, 0.f, 0.f};

  const char* ga = (const char*)(A + (size_t)m0 * Kdim);
  const char* gb = (const char*)(Bt + (size_t)n0 * Kdim);
  auto stageA = [&](int b, int ks) {
    const int k0b = ks << 7;                       // byte offset of K-tile
    char* Ab = smem + b * ABYTES;
#pragma unroll
    for (int i = 0; i < ACH; ++i) {
      const int doff = (wid * ACH + i) << 10;
      const int boff = doff + lane * 16;
      const int row = boff >> 7;
      const int src = row * ldb + k0b + ((boff & 127) ^ ((row & 7) << 4));
      gload16(ga + src, Ab + doff);
    }
  };
  auto stageB = [&](int ks) {
    const int k0b = ks << 7;
    char* Bb = smem + 2 * ABYTES;
#pragma unroll
    for (int i = 0; i < BCH; ++i) {
      const int doff = (wid * BCH + i) << 10;
      const int boff = doff + lane * 16;
      const int row = boff >> 7;
      const int src = row * ldb + k0b + ((boff & 127) ^ ((row & 7) << 4));
      gload16(gb + src, Bb + doff);
    }
  };

  const int nk = Kdim >> 6;
  stageA(0, 0);                                    // prologue
  stageB(0);
  __syncthreads();

  int cur = 0;
  for (int ks = 0; ks < nk; ++ks) {
    const int ksn = (ks + 1 < nk) ? ks + 1 : ks;   // clamped tail re-stage
    const char* Ab = smem + cur * ABYTES;
    const char* Bb = smem + 2 * ABYTES;
    // ---- hoist ALL B-frags (both kk) + A kk0 frags to registers
    bf8_t bfv[2][NI], af0[4];
#pragma unroll
    for (int kk = 0; kk < 2; ++kk)
#pragma unroll
      for (int ni = 0; ni < NI; ++ni) {
        int lrow = wc * WNW + (ni << 4) + cl;
        bfv[kk][ni] = *(const bf8_t*)&Bb[(lrow << 7) + ((((kk << 2) + g) ^ (lrow & 7)) << 4)];
      }
#pragma unroll
    for (int mi = 0; mi < 4; ++mi) {
      int lrow = (wr << 6) + (mi << 4) + cl;
      af0[mi] = *(const bf8_t*)&Ab[(lrow << 7) + (((g) ^ (lrow & 7)) << 4)];
    }
    __syncthreads();                               // barrier1: B consumed
    stageA(cur ^ 1, ksn);                          // prefetch next tiles
    stageB(ksn);                                   // same B buffer (now dead)
#pragma unroll
    for (int mi = 0; mi < 4; ++mi)
#pragma unroll
      for (int ni = 0; ni < NI; ++ni)
        acc[mi][ni] = MFMA16(af0[mi], bfv[0][ni], acc[mi][ni]);
    bf8_t af1[4];
#pragma unroll
    for (int mi = 0; mi < 4; ++mi) {
      int lrow = (wr << 6) + (mi << 4) + cl;
      af1[mi] = *(const bf8_t*)&Ab[(lrow << 7) + (((4 + g) ^ (lrow & 7)) << 4)];
    }
#pragma unroll
    for (int mi = 0; mi < 4; ++mi)
#pragma unroll
      for (int ni = 0; ni < NI; ++ni)
        acc[mi][ni] = MFMA16(af1[mi], bfv[1][ni], acc[mi][ni]);
    __syncthreads();                               // barrier2: drains stage
    cur ^= 1;
  }

  // epilogue.  C/D layout: col = lane&15, row = (lane>>4)*4 + r
  if constexpr (EPI == 1) {
#pragma unroll
    for (int ni = 0; ni < NI; ++ni) {
      const int n = n0 + wc * WNW + (ni << 4) + cl;
      const float bv = bias[n];
#pragma unroll
      for (int mi = 0; mi < 4; ++mi)
#pragma unroll
        for (int r = 0; r < 4; ++r) {
          const int m = m0 + (wr << 6) + (mi << 4) + (g << 2) + r;
          outF[(size_t)m * 768 + n] = acc[mi][ni][r] + bv;
        }
    }
  } else {
    // ---- per 128-row half: stage C (bf16, +bias, q-scaled) into LDS
    // T[128][132], column-group XOR-swizzled (group' = (col>>3)^((row>>3)&7))
    short* T = (short*)smem;
    const int sec = n0 / 768;                      // block-uniform section
    const float qs = (sec == 0) ? kQscale : 1.0f;
#pragma unroll
    for (int mh = 0; mh < BM / 128; ++mh) {
      if ((wr >> 1) == mh) {                       // wave-uniform write phase
#pragma unroll
        for (int ni = 0; ni < NI; ++ni) {
          const int colT = wc * WNW + (ni << 4) + cl;
          const float bv = bias[n0 + colT];
#pragma unroll
          for (int mi = 0; mi < 4; ++mi)
#pragma unroll
            for (int r = 0; r < 4; ++r) {
              const int row = (wr << 6) + (mi << 4) + (g << 2) + r - (mh << 7);
              const int colS = ((((colT >> 3) ^ ((row >> 3) & 7)) << 3) | (colT & 7));
              T[row * 132 + colS] = f2bs((acc[mi][ni][r] + bv) * qs);
            }
        }
      }
      __syncthreads();
      if (sec < 2) {                               // q/k: [bh][t][d] rows
        short* dst0 = (sec == 0) ? qb : kb;
        const int tl = tid & 127;                  // row in half-tile
        const int hh2 = (tid >> 7) & 1;            // head slice (BN=128 -> 2)
        const int half = tid >> 8;                 // 0/1 (NT=512)
        constexpr int JN = (NT == 256) ? 8 : 4;    // bf8 chunks per thread
        const int m = m0 + (mh << 7) + tl, b = m >> 11, t = m & 2047;
        const int hh = ((n0 - sec * 768) >> 6) + hh2;
        short* dst = dst0 + (size_t)(b * 12 + hh) * 131072 + (size_t)t * 64 + half * 32;
        const int rsw = (tl >> 3) & 7;
#pragma unroll
        for (int j = 0; j < JN; ++j) {
          const int gj = (hh2 << 3) + (half << 2) + j;  // logical col group
          *(bf8_t*)(dst + j * 8) =
              *(const bf8_t*)(T + tl * 132 + ((gj ^ rsw) << 3));
        }
      } else {                                     // v: transpose -> [bh][d][t]
        const int chunk = tid & 15;                // 8-t run per 16-lane group
        constexpr int DLS = NT >> 4;               // 16 or 32
        const int m = m0 + (mh << 7) + (chunk << 3);
        const int b = m >> 11, t = m & 2047;
#pragma unroll
        for (int c8 = 0; c8 < 128 / DLS; ++c8) {
          const int dl = (tid >> 4) + c8 * DLS;
          const int nloc = n0 - 1536 + dl;
          const int hh = nloc >> 6, d = nloc & 63;
          const int gsw = ((dl >> 3) ^ (chunk & 7)) << 3;  // row>>3 == chunk
          bf8_t tmp;
#pragma unroll
          for (int j = 0; j < 8; ++j)
            tmp[j] = T[((chunk << 3) + j) * 132 + gsw + (dl & 7)];
          *(bf8_t*)(vtb + (size_t)(b * 12 + hh) * 131072 + (size_t)d * 2048 + t) = tmp;
        }
      }
      __syncthreads();                             // store done before next mh
    }
  }
}

// ---------------------------------------------------------- flash attention
// R20 (kept): 8-wave blocks. 384 blocks (48 bh x 8 qg) x 512 thr; 8 q-tiles
// share one K/V stream (64KB dbuf; staging wid 0-3 = K, 4-7 = V). Compute
// body (R17): swapped QK^T, fixed-max exp2 softmax, deferred l, cvt_pk +
// 2 permlane32_swap P^T assembly.
__global__ __launch_bounds__(512) void attn_fwd(const short* __restrict__ Q,
                                                const short* __restrict__ K,
                                                const short* __restrict__ Vt,
                                                short* __restrict__ O) {
  __shared__ char kv_lds[2][32768];                // [buf][ K 16KB | V 16KB ]
  const int tid = threadIdx.x;
  const int lane = tid & 63, wid = tid >> 6;       // wid 0-7
  const int blk = blockIdx.x;                      // 384 = 48 bh x 8 qg
  const int bh = blk % 48;                         // 48%8==0 -> bh pinned to XCD
  const int qg = 7 - blk / 48;                     // longest blocks first
  const int qt = (qg << 3) + wid;
  const int q0 = qt << 5;
  const int col = lane & 31, hi = lane >> 5;

  const short* Qb = Q + (size_t)bh * 131072;
  const short* Kb = K + (size_t)bh * 131072;
  const short* Vb = Vt + (size_t)bh * 131072;

  bf8_t qf[4];                                     // Q^T B-fragments (persist)
#pragma unroll
  for (int dc = 0; dc < 4; ++dc)
    qf[dc] = *(const bf8_t*)(Qb + (size_t)(q0 + col) * 64 + dc * 16 + hi * 8);

  const f16v_t zf = {0.f,0.f,0.f,0.f,0.f,0.f,0.f,0.f,0.f,0.f,0.f,0.f,0.f,0.f,0.f,0.f};
  f16v_t o0 = zf, o1 = zf;
  float ls[4] = {0.f, 0.f, 0.f, 0.f};

  const int nt = (qg << 1) + 2;                    // 128-k tiles per block
  const int kxor = (col & 7) << 4;

  // ---- stage 128-k tile at kcs into buf b (waves 0-3: K; waves 4-7: V)
  auto stage = [&](int b, int kcs) {
    char* buf = &kv_lds[b][0];
    if (wid < 4) {
      const char* g = (const char*)(Kb + (size_t)kcs * 64);  // 16KB contiguous
#pragma unroll
      for (int i = 0; i < 4; ++i) {
        const int doff = (wid << 12) + (i << 10);
        const int boff = doff + lane * 16;
        const int src = boff ^ (((boff >> 7) & 7) << 4);
        gload16(g + src, buf + doff);
      }
    } else {
      const char* g = (const char*)Vb + (size_t)kcs * 2;     // rows stride 4KB
#pragma unroll
      for (int i = 0; i < 4; ++i) {
        const int doff = ((wid - 4) << 12) + (i << 10);
        const int boff = doff + lane * 16;
        const int row = boff >> 8;                 // 64 rows x 256B
        const int src = row * 4096 + ((boff & 255) ^ ((row & 7) << 4));
        gload16(g + src, buf + 16384 + doff);
      }
    }
  };

  stage(0, 0);                                     // prologue
  __syncthreads();                                 // drains gload vmcnt

  int cur = 0;
  for (int st = 0; st < nt; ++st) {
    int kcn = (st + 1) << 7;                       // next tile (clamped in-bounds)
    if (kcn > 1920) kcn = 1920;
    stage(cur ^ 1, kcn);

#pragma unroll
    for (int h = 0; h < 2; ++h) {
      const int kc = (st << 7) + (h << 6);
      if (kc < q0 + 32) {                          // per-wave-uniform skip
        const char* Kl = &kv_lds[cur][h << 13];    // 64 k-rows x 128B
        const char* Vl = &kv_lds[cur][16384];      // 64 d-rows x 256B
        // ---- QK^T (8 MFMA) from LDS
        f16v_t s0 = zf, s1 = zf;
#pragma unroll
        for (int dc = 0; dc < 4; ++dc) {
          const int fo = (dc * 32 + hi * 16) ^ kxor;
          bf8_t k0 = *(const bf8_t*)(Kl + col * 128 + fo);
          bf8_t k1 = *(const bf8_t*)(Kl + (32 + col) * 128 + fo);
          __builtin_amdgcn_s_setprio(1);
          s0 = MFMA32(k0, qf[dc], s0);
          s1 = MFMA32(k1, qf[dc], s1);
          __builtin_amdgcn_s_setprio(0);
        }
        // ---- causal mask (diagonal-crossing halves only)
        if (kc + 63 > q0) {
          const int qq = q0 + col;
#pragma unroll
          for (int r = 0; r < 16; ++r) {
            const int kb_ = kc + (r & 3) + 8 * (r >> 2) + 4 * hi;
            if (kb_ > qq) s0[r] = -1e30f;
            if (kb_ + 32 > qq) s1[r] = -1e30f;
          }
        }
        // ---- P = exp2(s) (fixed max; masked -> 0)
#pragma unroll
        for (int r = 0; r < 16; ++r) {
          s0[r] = __builtin_amdgcn_exp2f(s0[r]);
          s1[r] = __builtin_amdgcn_exp2f(s1[r]);
        }
#pragma unroll
        for (int r = 0; r < 4; ++r)
          ls[r] += ((s0[r] + s0[r + 4]) + (s0[r + 8] + s0[r + 12])) +
                   ((s1[r] + s1[r + 4]) + (s1[r + 8] + s1[r + 12]));
        // ---- PV: P^T frags via cvt_pk + 2 permlane32_swap; V from LDS
#pragma unroll
        for (int c = 0; c < 4; ++c) {
          const int b8 = (c & 1) * 8;
          float p0, p1, p2, p3, p4, p5, p6, p7;
          if (c < 2) {
            p0 = s0[b8+0]; p1 = s0[b8+1]; p2 = s0[b8+2]; p3 = s0[b8+3];
            p4 = s0[b8+4]; p5 = s0[b8+5]; p6 = s0[b8+6]; p7 = s0[b8+7];
          } else {
            p0 = s1[b8+0]; p1 = s1[b8+1]; p2 = s1[b8+2]; p3 = s1[b8+3];
            p4 = s1[b8+4]; p5 = s1[b8+5]; p6 = s1[b8+6]; p7 = s1[b8+7];
          }
          unsigned w0 = cvtpk(p0, p1), w1 = cvtpk(p2, p3);
          unsigned w2 = cvtpk(p4, p5), w3 = cvtpk(p6, p7);
          u2_t ra = __builtin_amdgcn_permlane32_swap(w0, w2, false, false);
          u2_t rb = __builtin_amdgcn_permlane32_swap(w1, w3, false, false);
          const bf8_t pf = __builtin_bit_cast(bf8_t, (u4_t){ra[0], rb[0], ra[1], rb[1]});
          const int vo = ((h << 7) + c * 32 + hi * 16) ^ kxor;
          bf8_t v0 = *(const bf8_t*)(Vl + col * 256 + vo);
          bf8_t v1 = *(const bf8_t*)(Vl + (32 + col) * 256 + vo);
          __builtin_amdgcn_s_setprio(1);
          o0 = MFMA32(v0, pf, o0);
          o1 = MFMA32(v1, pf, o1);
          __builtin_amdgcn_s_setprio(0);
        }
      }
    }
    __syncthreads();                               // stage drained, bufs flip
    cur ^= 1;
  }

  // ---- final l reduction + write O[b][t][h*64+d] bf16
  const float l = red2_sum((ls[0] + ls[1]) + (ls[2] + ls[3]));
  const float rl = 1.0f / l;
  const int b_ = bh / 12, hh = bh % 12;
  short* Op = O + (size_t)b_ * 2048 * 768 + (size_t)(q0 + col) * 768 + hh * 64;
#pragma unroll
  for (int rq = 0; rq < 4; ++rq) {
    u2_t w0, w1;
    w0[0] = cvtpk(o0[4*rq+0] * rl, o0[4*rq+1] * rl);
    w0[1] = cvtpk(o0[4*rq+2] * rl, o0[4*rq+3] * rl);
    w1[0] = cvtpk(o1[4*rq+0] * rl, o1[4*rq+1] * rl);
    w1[1] = cvtpk(o1[4*rq+2] * rl, o1[4*rq+3] * rl);
    *(u2_t*)(Op + rq * 8 + hi * 4) = w0;
    *(u2_t*)(Op + 32 + rq * 8 + hi * 4) = w1;
  }
}

// ------------------------------------------------------------------- launch
extern "C" void kernel_launch(void* const* d_in, const int* in_sizes, int n_in,
                              void* d_out, int out_size, void* d_ws, size_t ws_size,
                              hipStream_t stream) {
  const float* x      = (const float*)d_in[0];
  const float* w_attn = (const float*)d_in[1];
  const float* b_attn = (const float*)d_in[2];
  const float* w_proj = (const float*)d_in[3];
  const float* b_proj = (const float*)d_in[4];
  float* out = (float*)d_out;

  const size_t QSZ = (size_t)4 * 12 * 2048 * 64;   // 6291456 elems
  short* ws  = (short*)d_ws;
  short* qb  = ws;
  short* kb  = qb + QSZ;
  short* vtb = kb + QSZ;
  short* xb  = vtb + QSZ;                          // x bf16; reused as O after GEMM1
  short* ob  = xb;                                 // alias (GEMM1 done before attn)
  short* wat = xb + QSZ;                           // w_attn^T bf16 [2304][768]
  short* wpt = wat + (size_t)2304 * 768;           // w_proj^T bf16 [768][768]

  prep<<<5376, 256, 0, stream>>>(x, xb, w_attn, wat, w_proj, wpt);

  gemm_bf16<0, 256, 128, 8><<<dim3(18, 32), 512, 0, stream>>>(
      xb, wat, b_attn, nullptr, qb, kb, vtb, 8192, 2304, 768);
  attn_fwd<<<384, 512, 0, stream>>>(qb, kb, vtb, ob);
  gemm_bf16<1, 128, 64, 8><<<dim3(12, 64), 512, 0, stream>>>(
      ob, wpt, b_proj, out, nullptr, nullptr, nullptr, 8192, 768, 768);
}

// Round 23
// 114.149 us; speedup vs baseline: 1.0455x; 1.0455x over previous
//
#include <hip/hip_runtime.h>
#include <cstdint>
#include <cstddef>

typedef __attribute__((ext_vector_type(8))) short bf8_t;    // 8 x bf16 bits
typedef __attribute__((ext_vector_type(4))) float f4_t;
typedef __attribute__((ext_vector_type(16))) float f16v_t;
typedef __attribute__((ext_vector_type(2))) unsigned u2_t;
typedef __attribute__((ext_vector_type(4))) unsigned u4_t;

#define DEVFN static __device__ __forceinline__
#define MFMA16(a, b, c) __builtin_amdgcn_mfma_f32_16x16x32_bf16(a, b, c, 0, 0, 0)
#define MFMA32(a, b, c) __builtin_amdgcn_mfma_f32_32x32x16_bf16(a, b, c, 0, 0, 0)

// 768^-0.5 * log2(e): folded into Q at GEMM1 epilogue; attn uses exp2 directly.
constexpr float kQscale = 0.05205877317700523f;

DEVFN short f2bs(float f) {  // f32 -> bf16 bits, RNE
  uint32_t u = __builtin_bit_cast(uint32_t, f);
  u = (u + 0x7FFFu + ((u >> 16) & 1u)) >> 16;
  return (short)(uint16_t)u;
}

DEVFN unsigned cvtpk(float lo, float hi) {  // packed bf16(lo) | bf16(hi)<<16
  unsigned r;
  asm("v_cvt_pk_bf16_f32 %0, %1, %2" : "=v"(r) : "v"(lo), "v"(hi));
  return r;
}

DEVFN float red2_sum(float v) { return v + __shfl_xor(v, 32, 64); }

// async global->LDS, 16B/lane; dest = lds_ptr + lane*16 (wave-uniform base)
DEVFN void gload16(const void* g, void* l) {
  __builtin_amdgcn_global_load_lds(
      (const __attribute__((address_space(1))) void*)g,
      (__attribute__((address_space(3))) void*)l, 16, 0, 0);
}

// -------------------------------------------- fused pre-pass (1 launch, was 3)
// blocks [0,3072): x f32 -> bf16;  [3072,4800): w_attn^T;  [4800,5376): w_proj^T
__global__ __launch_bounds__(256) void prep(const float* __restrict__ x,
                                            short* __restrict__ xb,
                                            const float* __restrict__ w_attn,
                                            short* __restrict__ wat,
                                            const float* __restrict__ w_proj,
                                            short* __restrict__ wpt) {
  __shared__ float tile[32][33];
  const int blk = blockIdx.x, tid = threadIdx.x;
  if (blk < 3072) {                                // cvt: one bf8 chunk/thread
    const int i = blk * 256 + tid;
    const f4_t* p = (const f4_t*)x + (size_t)i * 2;
    f4_t a = p[0], b = p[1];
    bf8_t h;
    h[0] = f2bs(a[0]); h[1] = f2bs(a[1]); h[2] = f2bs(a[2]); h[3] = f2bs(a[3]);
    h[4] = f2bs(b[0]); h[5] = f2bs(b[1]); h[6] = f2bs(b[2]); h[7] = f2bs(b[3]);
    *((bf8_t*)xb + i) = h;
    return;
  }
  const float* w;
  short* wT;
  int N, n0, k0;
  if (blk < 4800) {                                // w_attn [768][2304] -> ^T
    const int bb = blk - 3072;
    w = w_attn; wT = wat; N = 2304;
    n0 = (bb % 72) << 5; k0 = (bb / 72) << 5;
  } else {                                         // w_proj [768][768] -> ^T
    const int bb = blk - 4800;
    w = w_proj; wT = wpt; N = 768;
    n0 = (bb % 24) << 5; k0 = (bb / 24) << 5;
  }
  const int tx = tid & 31, ty = tid >> 5;          // (32, 8)
#pragma unroll
  for (int i = 0; i < 4; ++i)
    tile[ty * 4 + i][tx] = w[(size_t)(k0 + ty * 4 + i) * N + n0 + tx];
  __syncthreads();
#pragma unroll
  for (int i = 0; i < 4; ++i)
    wT[(size_t)(n0 + ty * 4 + i) * 768 + k0 + tx] = f2bs(tile[tx][ty * 4 + i]);
}

// ------------------------------------------------------------------ bf16 GEMM
// C[M][N] = A[M][K] @ Bt[N][K]^T + bias.  128xBN tile, BK=64, NW waves.
// R23 = R21 exact (measured optimum 46.8us, Occ 41%): A double-buffered
// (32KB) + B single-buffered via reg-hoist (B-frags+A-kk0 to regs ->
// barrier1 -> stage A(t+1)^buf + B(t+1) same buffer -> MFMA kk0 -> A-kk1
// frags -> MFMA kk1 -> barrier2). Probed and rejected: NW=4 (slower),
// A-single-buffer (R20: +7us), BM=256 (R22: +17us, FETCH dropped but
// critical path doubled), 8-phase (R11: +43us at this shape).
// + XCD-grouped swizzle, gload_lds(16B) pre-swizzled source, LDS-routed
// EPI=0 epilogue w/ col-group swizzle (R13/R18).
template <int EPI, int BN, int NW>
__global__ __launch_bounds__(NW * 64) void gemm_bf16(
    const short* __restrict__ A, const short* __restrict__ Bt,
    const float* __restrict__ bias, float* __restrict__ outF,
    short* __restrict__ qb, short* __restrict__ kb, short* __restrict__ vtb,
    int Mdim, int Ndim, int Kdim) {
  constexpr int NT = NW * 64;                      // threads
  constexpr int WCN = NW / 2;                      // waves in n-dir
  constexpr int WNW = BN / WCN;                    // wave n-width
  constexpr int NI = WNW / 16;                     // n-frags per wave
  constexpr int ACH = 16 / NW;                     // A 1KB chunks per wave
  constexpr int BCH = BN / (8 * NW);               // B 1KB chunks per wave
  __shared__ char smem[32768 + (BN << 7)];         // A dbuf 32KB | B single
  const int nbx = gridDim.x;
  const int bid = blockIdx.x + nbx * blockIdx.y;
  const int xcd = bid & 7, slot = bid >> 3;        // dispatch round-robins XCDs
  const int mp = xcd + ((slot / nbx) << 3);        // bijective remap
  const int np = slot % nbx;
  const int m0 = mp << 7, n0 = np * BN;
  const int tid = threadIdx.x;
  const int lane = tid & 63, wid = tid >> 6;
  const int wr = wid / WCN, wc = wid % WCN;
  const int g = lane >> 4, cl = lane & 15;
  const int ldb = Kdim << 1;                       // global row stride, bytes

  f4_t acc[4][NI];
#pragma unroll
  for (int mi = 0; mi < 4; ++mi)
#pragma unroll
    for (int ni = 0; ni < NI; ++ni) acc[mi][ni] = (f4_t){0.f, 0.f, 0.f, 0.f};

  const char* ga = (const char*)(A + (size_t)m0 * Kdim);
  const char* gb = (const char*)(Bt + (size_t)n0 * Kdim);
  auto stageA = [&](int b, int ks) {
    const int k0b = ks << 7;                       // byte offset of K-tile
    char* Ab = smem + (b << 14);
#pragma unroll
    for (int i = 0; i < ACH; ++i) {                // A: 16KB
      const int doff = (wid * ACH + i) << 10;
      const int boff = doff + lane * 16;
      const int row = boff >> 7;
      const int src = row * ldb + k0b + ((boff & 127) ^ ((row & 7) << 4));
      gload16(ga + src, Ab + doff);
    }
  };
  auto stageB = [&](int ks) {
    const int k0b = ks << 7;
    char* Bb = smem + 32768;
#pragma unroll
    for (int i = 0; i < BCH; ++i) {                // B: BN<<7 bytes
      const int doff = (wid * BCH + i) << 10;
      const int boff = doff + lane * 16;
      const int row = boff >> 7;
      const int src = row * ldb + k0b + ((boff & 127) ^ ((row & 7) << 4));
      gload16(gb + src, Bb + doff);
    }
  };

  const int nk = Kdim >> 6;
  stageA(0, 0);                                    // prologue
  stageB(0);
  __syncthreads();

  int cur = 0;
  for (int ks = 0; ks < nk; ++ks) {
    const int ksn = (ks + 1 < nk) ? ks + 1 : ks;   // clamped tail re-stage
    const char* Ab = smem + (cur << 14);
    const char* Bb = smem + 32768;
    // ---- hoist ALL B-frags (both kk) + A kk0 frags to registers
    bf8_t bfv[2][NI], af0[4];
#pragma unroll
    for (int kk = 0; kk < 2; ++kk)
#pragma unroll
      for (int ni = 0; ni < NI; ++ni) {
        int lrow = wc * WNW + (ni << 4) + cl;
        bfv[kk][ni] = *(const bf8_t*)&Bb[(lrow << 7) + ((((kk << 2) + g) ^ (lrow & 7)) << 4)];
      }
#pragma unroll
    for (int mi = 0; mi < 4; ++mi) {
      int lrow = (wr << 6) + (mi << 4) + cl;
      af0[mi] = *(const bf8_t*)&Ab[(lrow << 7) + (((g) ^ (lrow & 7)) << 4)];
    }
    __syncthreads();                               // barrier1: B consumed
    stageA(cur ^ 1, ksn);                          // prefetch next tiles
    stageB(ksn);                                   // same B buffer (now dead)
#pragma unroll
    for (int mi = 0; mi < 4; ++mi)
#pragma unroll
      for (int ni = 0; ni < NI; ++ni)
        acc[mi][ni] = MFMA16(af0[mi], bfv[0][ni], acc[mi][ni]);
    bf8_t af1[4];
#pragma unroll
    for (int mi = 0; mi < 4; ++mi) {
      int lrow = (wr << 6) + (mi << 4) + cl;
      af1[mi] = *(const bf8_t*)&Ab[(lrow << 7) + (((4 + g) ^ (lrow & 7)) << 4)];
    }
#pragma unroll
    for (int mi = 0; mi < 4; ++mi)
#pragma unroll
      for (int ni = 0; ni < NI; ++ni)
        acc[mi][ni] = MFMA16(af1[mi], bfv[1][ni], acc[mi][ni]);
    __syncthreads();                               // barrier2: drains stage
    cur ^= 1;
  }

  // epilogue.  C/D layout: col = lane&15, row = (lane>>4)*4 + r
  if constexpr (EPI == 1) {
#pragma unroll
    for (int ni = 0; ni < NI; ++ni) {
      const int n = n0 + wc * WNW + (ni << 4) + cl;
      const float bv = bias[n];
#pragma unroll
      for (int mi = 0; mi < 4; ++mi)
#pragma unroll
        for (int r = 0; r < 4; ++r) {
          const int m = m0 + (wr << 6) + (mi << 4) + (g << 2) + r;
          outF[(size_t)m * 768 + n] = acc[mi][ni][r] + bv;
        }
    }
  } else {
    // ---- stage C-tile (bf16, +bias, q-scaled) into LDS T[128][132],
    // column-group XOR-swizzled: group' = (col>>3) ^ ((row>>3)&7)
    short* T = (short*)smem;
    const int sec = n0 / 768;                      // block-uniform section
    const float qs = (sec == 0) ? kQscale : 1.0f;
#pragma unroll
    for (int ni = 0; ni < NI; ++ni) {
      const int colT = wc * WNW + (ni << 4) + cl;
      const float bv = bias[n0 + colT];
#pragma unroll
      for (int mi = 0; mi < 4; ++mi)
#pragma unroll
        for (int r = 0; r < 4; ++r) {
          const int row = (wr << 6) + (mi << 4) + (g << 2) + r;
          const int colS = ((((colT >> 3) ^ ((row >> 3) & 7)) << 3) | (colT & 7));
          T[row * 132 + colS] = f2bs((acc[mi][ni][r] + bv) * qs);
        }
    }
    __syncthreads();
    if (sec < 2) {                                 // q/k: [bh][t][d] rows
      short* dst0 = (sec == 0) ? qb : kb;
      const int tl = tid & 127;                    // row in tile
      const int hh2 = (tid >> 7) & 1;              // head slice (BN=128 -> 2)
      const int half = tid >> 8;                   // 0 (NT=256) or 0/1 (NT=512)
      constexpr int JN = (NT == 256) ? 8 : 4;      // bf8 chunks per thread
      const int m = m0 + tl, b = m >> 11, t = m & 2047;
      const int hh = ((n0 - sec * 768) >> 6) + hh2;
      short* dst = dst0 + (size_t)(b * 12 + hh) * 131072 + (size_t)t * 64 + half * 32;
      const int rsw = (tl >> 3) & 7;
#pragma unroll
      for (int j = 0; j < JN; ++j) {
        const int gj = (hh2 << 3) + (half << 2) + j;   // logical col group
        *(bf8_t*)(dst + j * 8) =
            *(const bf8_t*)(T + tl * 132 + ((gj ^ rsw) << 3));
      }
    } else {                                       // v: transpose -> [bh][d][t]
      const int chunk = tid & 15;                  // 8-t run; lanes 0-15 -> 256B
      constexpr int DLS = NT >> 4;                 // 16 or 32
      const int m = m0 + (chunk << 3);
      const int b = m >> 11, t = m & 2047;
#pragma unroll
      for (int c8 = 0; c8 < 128 / DLS; ++c8) {
        const int dl = (tid >> 4) + c8 * DLS;
        const int nloc = n0 - 1536 + dl;
        const int hh = nloc >> 6, d = nloc & 63;
        const int gsw = ((dl >> 3) ^ (chunk & 7)) << 3;  // row>>3 == chunk
        bf8_t tmp;
#pragma unroll
        for (int j = 0; j < 8; ++j)
          tmp[j] = T[((chunk << 3) + j) * 132 + gsw + (dl & 7)];
        *(bf8_t*)(vtb + (size_t)(b * 12 + hh) * 131072 + (size_t)d * 2048 + t) = tmp;
      }
    }
  }
}

// ---------------------------------------------------------- flash attention
// R20 (kept): 8-wave blocks. 384 blocks (48 bh x 8 qg) x 512 thr; 8 q-tiles
// share one K/V stream (64KB dbuf; staging wid 0-3 = K, 4-7 = V). Compute
// body (R17): swapped QK^T, fixed-max exp2 softmax, deferred l, cvt_pk +
// 2 permlane32_swap P^T assembly.
__global__ __launch_bounds__(512) void attn_fwd(const short* __restrict__ Q,
                                                const short* __restrict__ K,
                                                const short* __restrict__ Vt,
                                                short* __restrict__ O) {
  __shared__ char kv_lds[2][32768];                // [buf][ K 16KB | V 16KB ]
  const int tid = threadIdx.x;
  const int lane = tid & 63, wid = tid >> 6;       // wid 0-7
  const int blk = blockIdx.x;                      // 384 = 48 bh x 8 qg
  const int bh = blk % 48;                         // 48%8==0 -> bh pinned to XCD
  const int qg = 7 - blk / 48;                     // longest blocks first
  const int qt = (qg << 3) + wid;
  const int q0 = qt << 5;
  const int col = lane & 31, hi = lane >> 5;

  const short* Qb = Q + (size_t)bh * 131072;
  const short* Kb = K + (size_t)bh * 131072;
  const short* Vb = Vt + (size_t)bh * 131072;

  bf8_t qf[4];                                     // Q^T B-fragments (persist)
#pragma unroll
  for (int dc = 0; dc < 4; ++dc)
    qf[dc] = *(const bf8_t*)(Qb + (size_t)(q0 + col) * 64 + dc * 16 + hi * 8);

  const f16v_t zf = {0.f,0.f,0.f,0.f,0.f,0.f,0.f,0.f,0.f,0.f,0.f,0.f,0.f,0.f,0.f,0.f};
  f16v_t o0 = zf, o1 = zf;
  float ls[4] = {0.f, 0.f, 0.f, 0.f};

  const int nt = (qg << 1) + 2;                    // 128-k tiles per block
  const int kxor = (col & 7) << 4;

  // ---- stage 128-k tile at kcs into buf b (waves 0-3: K; waves 4-7: V)
  auto stage = [&](int b, int kcs) {
    char* buf = &kv_lds[b][0];
    if (wid < 4) {
      const char* g = (const char*)(Kb + (size_t)kcs * 64);  // 16KB contiguous
#pragma unroll
      for (int i = 0; i < 4; ++i) {
        const int doff = (wid << 12) + (i << 10);
        const int boff = doff + lane * 16;
        const int src = boff ^ (((boff >> 7) & 7) << 4);
        gload16(g + src, buf + doff);
      }
    } else {
      const char* g = (const char*)Vb + (size_t)kcs * 2;     // rows stride 4KB
#pragma unroll
      for (int i = 0; i < 4; ++i) {
        const int doff = ((wid - 4) << 12) + (i << 10);
        const int boff = doff + lane * 16;
        const int row = boff >> 8;                 // 64 rows x 256B
        const int src = row * 4096 + ((boff & 255) ^ ((row & 7) << 4));
        gload16(g + src, buf + 16384 + doff);
      }
    }
  };

  stage(0, 0);                                     // prologue
  __syncthreads();                                 // drains gload vmcnt

  int cur = 0;
  for (int st = 0; st < nt; ++st) {
    int kcn = (st + 1) << 7;                       // next tile (clamped in-bounds)
    if (kcn > 1920) kcn = 1920;
    stage(cur ^ 1, kcn);

#pragma unroll
    for (int h = 0; h < 2; ++h) {
      const int kc = (st << 7) + (h << 6);
      if (kc < q0 + 32) {                          // per-wave-uniform skip
        const char* Kl = &kv_lds[cur][h << 13];    // 64 k-rows x 128B
        const char* Vl = &kv_lds[cur][16384];      // 64 d-rows x 256B
        // ---- QK^T (8 MFMA) from LDS
        f16v_t s0 = zf, s1 = zf;
#pragma unroll
        for (int dc = 0; dc < 4; ++dc) {
          const int fo = (dc * 32 + hi * 16) ^ kxor;
          bf8_t k0 = *(const bf8_t*)(Kl + col * 128 + fo);
          bf8_t k1 = *(const bf8_t*)(Kl + (32 + col) * 128 + fo);
          __builtin_amdgcn_s_setprio(1);
          s0 = MFMA32(k0, qf[dc], s0);
          s1 = MFMA32(k1, qf[dc], s1);
          __builtin_amdgcn_s_setprio(0);
        }
        // ---- causal mask (diagonal-crossing halves only)
        if (kc + 63 > q0) {
          const int qq = q0 + col;
#pragma unroll
          for (int r = 0; r < 16; ++r) {
            const int kb_ = kc + (r & 3) + 8 * (r >> 2) + 4 * hi;
            if (kb_ > qq) s0[r] = -1e30f;
            if (kb_ + 32 > qq) s1[r] = -1e30f;
          }
        }
        // ---- P = exp2(s) (fixed max; masked -> 0)
#pragma unroll
        for (int r = 0; r < 16; ++r) {
          s0[r] = __builtin_amdgcn_exp2f(s0[r]);
          s1[r] = __builtin_amdgcn_exp2f(s1[r]);
        }
#pragma unroll
        for (int r = 0; r < 4; ++r)
          ls[r] += ((s0[r] + s0[r + 4]) + (s0[r + 8] + s0[r + 12])) +
                   ((s1[r] + s1[r + 4]) + (s1[r + 8] + s1[r + 12]));
        // ---- PV: P^T frags via cvt_pk + 2 permlane32_swap; V from LDS
#pragma unroll
        for (int c = 0; c < 4; ++c) {
          const int b8 = (c & 1) * 8;
          float p0, p1, p2, p3, p4, p5, p6, p7;
          if (c < 2) {
            p0 = s0[b8+0]; p1 = s0[b8+1]; p2 = s0[b8+2]; p3 = s0[b8+3];
            p4 = s0[b8+4]; p5 = s0[b8+5]; p6 = s0[b8+6]; p7 = s0[b8+7];
          } else {
            p0 = s1[b8+0]; p1 = s1[b8+1]; p2 = s1[b8+2]; p3 = s1[b8+3];
            p4 = s1[b8+4]; p5 = s1[b8+5]; p6 = s1[b8+6]; p7 = s1[b8+7];
          }
          unsigned w0 = cvtpk(p0, p1), w1 = cvtpk(p2, p3);
          unsigned w2 = cvtpk(p4, p5), w3 = cvtpk(p6, p7);
          u2_t ra = __builtin_amdgcn_permlane32_swap(w0, w2, false, false);
          u2_t rb = __builtin_amdgcn_permlane32_swap(w1, w3, false, false);
          const bf8_t pf = __builtin_bit_cast(bf8_t, (u4_t){ra[0], rb[0], ra[1], rb[1]});
          const int vo = ((h << 7) + c * 32 + hi * 16) ^ kxor;
          bf8_t v0 = *(const bf8_t*)(Vl + col * 256 + vo);
          bf8_t v1 = *(const bf8_t*)(Vl + (32 + col) * 256 + vo);
          __builtin_amdgcn_s_setprio(1);
          o0 = MFMA32(v0, pf, o0);
          o1 = MFMA32(v1, pf, o1);
          __builtin_amdgcn_s_setprio(0);
        }
      }
    }
    __syncthreads();                               // stage drained, bufs flip
    cur ^= 1;
  }

  // ---- final l reduction + write O[b][t][h*64+d] bf16
  const float l = red2_sum((ls[0] + ls[1]) + (ls[2] + ls[3]));
  const float rl = 1.0f / l;
  const int b_ = bh / 12, hh = bh % 12;
  short* Op = O + (size_t)b_ * 2048 * 768 + (size_t)(q0 + col) * 768 + hh * 64;
#pragma unroll
  for (int rq = 0; rq < 4; ++rq) {
    u2_t w0, w1;
    w0[0] = cvtpk(o0[4*rq+0] * rl, o0[4*rq+1] * rl);
    w0[1] = cvtpk(o0[4*rq+2] * rl, o0[4*rq+3] * rl);
    w1[0] = cvtpk(o1[4*rq+0] * rl, o1[4*rq+1] * rl);
    w1[1] = cvtpk(o1[4*rq+2] * rl, o1[4*rq+3] * rl);
    *(u2_t*)(Op + rq * 8 + hi * 4) = w0;
    *(u2_t*)(Op + 32 + rq * 8 + hi * 4) = w1;
  }
}

// ------------------------------------------------------------------- launch
extern "C" void kernel_launch(void* const* d_in, const int* in_sizes, int n_in,
                              void* d_out, int out_size, void* d_ws, size_t ws_size,
                              hipStream_t stream) {
  const float* x      = (const float*)d_in[0];
  const float* w_attn = (const float*)d_in[1];
  const float* b_attn = (const float*)d_in[2];
  const float* w_proj = (const float*)d_in[3];
  const float* b_proj = (const float*)d_in[4];
  float* out = (float*)d_out;

  const size_t QSZ = (size_t)4 * 12 * 2048 * 64;   // 6291456 elems
  short* ws  = (short*)d_ws;
  short* qb  = ws;
  short* kb  = qb + QSZ;
  short* vtb = kb + QSZ;
  short* xb  = vtb + QSZ;                          // x bf16; reused as O after GEMM1
  short* ob  = xb;                                 // alias (GEMM1 done before attn)
  short* wat = xb + QSZ;                           // w_attn^T bf16 [2304][768]
  short* wpt = wat + (size_t)2304 * 768;           // w_proj^T bf16 [768][768]

  prep<<<5376, 256, 0, stream>>>(x, xb, w_attn, wat, w_proj, wpt);

  gemm_bf16<0, 128, 8><<<dim3(18, 64), 512, 0, stream>>>(xb, wat, b_attn, nullptr,
                                                         qb, kb, vtb, 8192, 2304, 768);
  attn_fwd<<<384, 512, 0, stream>>>(qb, kb, vtb, ob);
  gemm_bf16<1, 64, 8><<<dim3(12, 64), 512, 0, stream>>>(ob, wpt, b_proj, out,
                                                        nullptr, nullptr, nullptr, 8192, 768, 768);
}